// Round 8
// baseline (176.835 us; speedup 1.0000x reference)
//
#include <hip/hip_runtime.h>

// AdaptiveConv2d v9: single fused conv — in-kernel NCHW->LDS bf16 transpose
// using the v8-proven pattern (lane=ci, per-lane contiguous float4 row
// reads, batch-issued; conflict-free b16 LDS writes), eliminating the xh
// intermediate (saves 70 MB round-trip + a kernel). Tile 32x8x64co so each
// lane's row read is 40 contiguous px. Tap loop / A-frag double-buffer /
// epilogue identical to v6 (bit-identical accumulation order).

typedef __bf16 bf16;
typedef __bf16 bf16x8 __attribute__((ext_vector_type(8)));
typedef float f32x4 __attribute__((ext_vector_type(4)));

#define NB 16
#define CI 64
#define CO 64
#define HH 128
#define WW 128
#define NKW 36864 // CO*CI*9
#define NROWS 36928
#define WT2_BYTES ((size_t)NB * 9 * 4096 * 2) // 1,179,648

typedef const __attribute__((address_space(1))) void* gas_ptr;
typedef __attribute__((address_space(3))) void* las_ptr;

// ---------------- hypernetwork ----------------
// grid 145 x 256. Thread owns one W2 row, loops the 16 samples; kernel
// rows land pre-swizzled for the conv A-fragment:
//   elem off = ((b*9+tap)*8 + g*2 + kh)*512 + (q*16+m)*8 + j
//   g=co>>4, m=co&15, kh=ci>>5, q=(ci>>3)&3, j=ci&7
__global__ __launch_bounds__(256)
void hyper_kernel(const float* __restrict__ z, const float* __restrict__ W0,
                  const float* __restrict__ b0, const float* __restrict__ W1,
                  const float* __restrict__ b1, const float* __restrict__ W2,
                  const float* __restrict__ b2, bf16* __restrict__ wt2,
                  float* __restrict__ biases) {
  __shared__ float h1s[NB][30];
  const int tid = threadIdx.x;
  if (tid < NB) {
    float h0[20];
    #pragma unroll
    for (int i = 0; i < 20; ++i) {
      float s = b0[i];
      #pragma unroll
      for (int j = 0; j < 16; ++j) s += W0[i * 16 + j] * z[tid * 16 + j];
      h0[i] = fmaxf(s, 0.f);
    }
    #pragma unroll
    for (int i = 0; i < 30; ++i) {
      float s = b1[i];
      #pragma unroll
      for (int j = 0; j < 20; ++j) s += W1[i * 20 + j] * h0[j];
      h1s[tid][i] = fmaxf(s, 0.f);
    }
  }
  __syncthreads();
  const int r = blockIdx.x * 256 + tid;
  if (r >= NROWS) return;
  float w2r[30];
  #pragma unroll
  for (int j = 0; j < 30; ++j) w2r[j] = W2[r * 30 + j];
  const float bb = b2[r];
  const bool isk = r < NKW;
  size_t base = 0;
  if (isk) {
    const int co = r / 576;
    const int rem = r - co * 576;
    const int ci = rem / 9;
    const int tap = rem - ci * 9;
    const int g = co >> 4, mm = co & 15;
    const int kh = ci >> 5, qq = (ci >> 3) & 3, jj = ci & 7;
    base = (size_t)(tap * 8 + g * 2 + kh) * 512 + (size_t)(qq * 16 + mm) * 8 + jj;
  }
  for (int b = 0; b < NB; ++b) {
    float s = bb;
    #pragma unroll
    for (int j = 0; j < 30; ++j) s += w2r[j] * h1s[b][j];
    s = fmaxf(s, 0.f);
    if (isk)
      wt2[(size_t)b * (9 * 4096) + base] = (bf16)s;
    else
      biases[b * CO + (r - NKW)] = s;
  }
}

// ---------------- fused conv (implicit GEMM, bf16 MFMA) ----------------
// 1D grid 1024, XCD-swizzled (XCD k <- samples 2k,2k+1). Block: 512 thr =
// 8 waves; tile = 32 px wide x 8 rows x all 64 co. Wave wv: output row
// y0+wv, acc[4 co-groups][2 px-halves]. Staging: wave wv stages input row
// y0-1+wv (waves 0,1 also rows +8): lane=ci, 10 aligned float4 (40 px)
// batch-issued, cvt, b16 writes into LDS [pl=py*36+pxl][ci] with XOR
// granule swizzle (2 lanes/bank = free). pxl = px-(x0-1), 0..33; borders
// zeroed block-uniformly. B reads = v4/v6-verified conflict-free b128.
// Weights: A-frags double-buffered in registers from L2. ONE barrier.
__global__ __launch_bounds__(512, 4)
void conv_fused(const float* __restrict__ x, const bf16* __restrict__ wt2,
                const float* __restrict__ bias, float* __restrict__ out) {
  __shared__ __align__(16) bf16 xt[360 * 64]; // 46,080 B

  const int id = (blockIdx.x & 7) * 128 + (blockIdx.x >> 3); // bijective
  const int b = id >> 6;
  const int rem = id & 63;
  const int x0 = (rem & 3) * 32;
  const int y0 = (rem >> 2) * 8;

  const int tid = threadIdx.x;
  const int lane = tid & 63;
  const int wv = tid >> 6; // 0..7
  const int m = lane & 15;
  const int q = lane >> 4;

  // ---- staging loads: batch-issue rows A (=wv) and B (=wv+8, wv<2) ----
  const int ci = lane;
  const float* xrow = x + (((size_t)b * CI + ci) << 14);
  const int gyA = y0 - 1 + wv;
  const int gyB = gyA + 8;
  const bool vA = (gyA >= 0) && (gyA < HH);
  const bool doB = (wv < 2);
  const bool vB = doB && (gyB < HH);

  float va[40], vb[40];
  if (vA) {
    const float* s = xrow + ((size_t)gyA << 7);
    #pragma unroll
    for (int jj = 0; jj < 10; ++jj) {
      const int bpx = min(max(x0 - 4 + 4 * jj, 0), WW - 4);
      *reinterpret_cast<f32x4*>(&va[4 * jj]) =
          *reinterpret_cast<const f32x4*>(s + bpx);
    }
  }
  if (vB) {
    const float* s = xrow + ((size_t)gyB << 7);
    #pragma unroll
    for (int jj = 0; jj < 10; ++jj) {
      const int bpx = min(max(x0 - 4 + 4 * jj, 0), WW - 4);
      *reinterpret_cast<f32x4*>(&vb[4 * jj]) =
          *reinterpret_cast<const f32x4*>(s + bpx);
    }
  }

  // ---- prefetch tap-0 A-fragments (overlaps staging latency) ----
  const char* wbase = (const char*)wt2 + (size_t)b * 73728 + lane * 16;
  bf16x8 abuf[2][4][2];
  #pragma unroll
  for (int i = 0; i < 4; ++i)
    #pragma unroll
    for (int kh = 0; kh < 2; ++kh)
      abuf[0][i][kh] =
          *reinterpret_cast<const bf16x8*>(wbase + (i * 2 + kh) * 1024);

  // ---- convert + conflict-free b16 LDS writes ----
  // value for pxl comes from va[pxl+3] (px = x0-1+pxl); borders zeroed.
  const bool zlo = (x0 == 0);        // pxl 0  -> px -1
  const bool zhi = (x0 == 96);       // pxl 33 -> px 128
  const int gq = ci >> 3, bo = (ci & 7) << 1;
  {
    const int py = wv;
    #pragma unroll
    for (int pxl = 0; pxl < 34; ++pxl) {
      bf16 v = (bf16)0.f;
      if (vA && !(pxl == 0 && zlo) && !(pxl == 33 && zhi)) v = (bf16)va[pxl + 3];
      const int pl = py * 36 + pxl;
      *reinterpret_cast<bf16*>(reinterpret_cast<char*>(xt) + (pl << 7) +
                               ((gq ^ (pl & 7)) << 4) + bo) = v;
    }
  }
  if (doB) {
    const int py = wv + 8;
    #pragma unroll
    for (int pxl = 0; pxl < 34; ++pxl) {
      bf16 v = (bf16)0.f;
      if (vB && !(pxl == 0 && zlo) && !(pxl == 33 && zhi)) v = (bf16)vb[pxl + 3];
      const int pl = py * 36 + pxl;
      *reinterpret_cast<bf16*>(reinterpret_cast<char*>(xt) + (pl << 7) +
                               ((gq ^ (pl & 7)) << 4) + bo) = v;
    }
  }

  f32x4 acc[4][2];
  #pragma unroll
  for (int i = 0; i < 4; ++i) {
    acc[i][0] = (f32x4){0.f, 0.f, 0.f, 0.f};
    acc[i][1] = (f32x4){0.f, 0.f, 0.f, 0.f};
  }

  __syncthreads(); // the only barrier

  #pragma unroll
  for (int tap = 0; tap < 9; ++tap) {
    const int cur = tap & 1, nxt = cur ^ 1; // compile-time after unroll
    if (tap < 8) { // prefetch next tap's A-frags; overlaps this tap's MFMAs
      const char* wt_n = wbase + (tap + 1) * 8192;
      #pragma unroll
      for (int i = 0; i < 4; ++i)
        #pragma unroll
        for (int kh = 0; kh < 2; ++kh)
          abuf[nxt][i][kh] =
              *reinterpret_cast<const bf16x8*>(wt_n + (i * 2 + kh) * 1024);
    }
    const int dy = (tap * 11) >> 5; // tap/3
    const int dx = tap - dy * 3;
    const int plb = (wv + dy) * 36 + dx + m; // pxl = n*16 + m + dx
    __builtin_amdgcn_s_setprio(1);
    #pragma unroll
    for (int kh = 0; kh < 2; ++kh) {
      const int qk = q + kh * 4;
      #pragma unroll
      for (int n = 0; n < 2; ++n) {
        const int pl = plb + n * 16;
        const bf16x8 bv = *reinterpret_cast<const bf16x8*>(
            reinterpret_cast<const char*>(xt) + (pl << 7) +
            ((qk ^ (pl & 7)) << 4));
        #pragma unroll
        for (int i = 0; i < 4; ++i)
          acc[i][n] = __builtin_amdgcn_mfma_f32_16x16x32_bf16(
              abuf[cur][i][kh], bv, acc[i][n], 0, 0, 0);
      }
    }
    __builtin_amdgcn_s_setprio(0);
  }

  // epilogue: D col = m (px), row = q*4+r (co in group); co = i*16 + q*4 + r
  const float* bp = bias + b * CO;
  float* ob = out + ((size_t)(b * CO) << 14) + (size_t)((y0 + wv) * WW + x0 + m);
  #pragma unroll
  for (int i = 0; i < 4; ++i)
    #pragma unroll
    for (int n = 0; n < 2; ++n)
      #pragma unroll
      for (int r = 0; r < 4; ++r) {
        const int co = i * 16 + q * 4 + r;
        float v = acc[i][n][r] + bp[co];
        ob[((size_t)co << 14) + n * 16] = fmaxf(v, 0.f);
      }
}

extern "C" void kernel_launch(void* const* d_in, const int* in_sizes, int n_in,
                              void* d_out, int out_size, void* d_ws,
                              size_t ws_size, hipStream_t stream) {
  const float* x = (const float*)d_in[0];
  const float* z = (const float*)d_in[1];
  const float* W0 = (const float*)d_in[2];
  const float* b0 = (const float*)d_in[3];
  const float* W1 = (const float*)d_in[4];
  const float* b1 = (const float*)d_in[5];
  const float* W2 = (const float*)d_in[6];
  const float* b2 = (const float*)d_in[7];
  float* out = (float*)d_out;

  // ws: wt2 bf16 fragment-layout [16][9][8 frag][512] | biases f32 [16][64]
  bf16* wt2 = (bf16*)d_ws;
  float* biases = (float*)((char*)d_ws + WT2_BYTES);

  hipLaunchKernelGGL(hyper_kernel, dim3((NROWS + 255) / 256), dim3(256), 0,
                     stream, z, W0, b0, W1, b1, W2, b2, wt2, biases);
  hipLaunchKernelGGL(conv_fused, dim3(1024), dim3(512), 0, stream, x, wt2,
                     biases, out);
}

// Round 9
// 164.985 us; speedup vs baseline: 1.0718x; 1.0718x over previous
//
#include <hip/hip_runtime.h>

// AdaptiveConv2d v10: v8 prep (hypernet + LDS-bounced NCHW->bordered-NHWC
// bf16 transpose) unchanged. Conv rebuilt BARRIER-FREE: each wave stages
// its own private 4-row x 18-px LDS region (9 global_load_lds, exact, no
// tail) and orders it with its OWN vmcnt — no __syncthreads, no block-wide
// staging convoy; waves self-stagger so staging overlaps compute across
// the CU. Swizzle pair (linear gll dest + inverse-swizzled source +
// swizzled b128 read) is the v4/v6-verified conflict-free pattern.

typedef __bf16 bf16;
typedef __bf16 bf16x8 __attribute__((ext_vector_type(8)));
typedef float f32x4 __attribute__((ext_vector_type(4)));

#define NB 16
#define CI 64
#define CO 64
#define HH 128
#define WW 128
#define TS 16
#define HALO 18           // TS + 2
#define NPL (HALO * HALO) // 324 halo pixels (fallback path)
#define NKW 36864         // CO*CI*9
#define NROWS 36928
#define XHW 130           // bordered NHWC width/height
#define WT2_BYTES ((size_t)NB * 9 * 4096 * 2)       // 1,179,648
#define BIAS_BYTES 4096
#define XH_BYTES ((size_t)NB * XHW * XHW * CI * 2)  // 34,611,200
#define WS_NEED (WT2_BYTES + BIAS_BYTES + XH_BYTES)

typedef const __attribute__((address_space(1))) void* gas_ptr;
typedef __attribute__((address_space(3))) void* las_ptr;

// ---------------- prep: hypernetwork + x transpose (v8, unchanged) ----------------
__global__ __launch_bounds__(256, 4)
void prep_kernel(const float* __restrict__ x, const float* __restrict__ z,
                 const float* __restrict__ W0, const float* __restrict__ b0,
                 const float* __restrict__ W1, const float* __restrict__ b1,
                 const float* __restrict__ W2, const float* __restrict__ b2,
                 bf16* __restrict__ wt2, float* __restrict__ biases,
                 bf16* __restrict__ xh) {
  const int tid = threadIdx.x;
  if (blockIdx.x < 145) {
    __shared__ float h1s[NB][30];
    if (tid < NB) {
      float h0[20];
      #pragma unroll
      for (int i = 0; i < 20; ++i) {
        float s = b0[i];
        #pragma unroll
        for (int j = 0; j < 16; ++j) s += W0[i * 16 + j] * z[tid * 16 + j];
        h0[i] = fmaxf(s, 0.f);
      }
      #pragma unroll
      for (int i = 0; i < 30; ++i) {
        float s = b1[i];
        #pragma unroll
        for (int j = 0; j < 20; ++j) s += W1[i * 20 + j] * h0[j];
        h1s[tid][i] = fmaxf(s, 0.f);
      }
    }
    __syncthreads();
    const int r = blockIdx.x * 256 + tid;
    if (r >= NROWS) return;
    float w2r[30];
    #pragma unroll
    for (int j = 0; j < 30; ++j) w2r[j] = W2[r * 30 + j];
    const float bb = b2[r];
    const bool isk = r < NKW;
    size_t base = 0;
    if (isk) {
      const int co = r / 576;
      const int rem = r - co * 576;
      const int ci = rem / 9;
      const int tap = rem - ci * 9;
      const int g = co >> 4, mm = co & 15;
      const int kh = ci >> 5, qq = (ci >> 3) & 3, jj = ci & 7;
      base = (size_t)(tap * 8 + g * 2 + kh) * 512 + (size_t)(qq * 16 + mm) * 8 + jj;
    }
    for (int b = 0; b < NB; ++b) {
      float s = bb;
      #pragma unroll
      for (int j = 0; j < 30; ++j) s += w2r[j] * h1s[b][j];
      s = fmaxf(s, 0.f);
      if (isk)
        wt2[(size_t)b * (9 * 4096) + base] = (bf16)s;
      else
        biases[b * CO + (r - NKW)] = s;
    }
    return;
  }

  // ---- transpose blocks: one (b, row-pair yp0, yp0+1) ----
  const int bi = blockIdx.x - 145;
  const int b = bi / 65;
  const int pr = bi - b * 65;
  const int yp0 = pr * 2;

  const int w = tid >> 6, lane = tid & 63;
  const int px0 = w * 32;

  bf16* row0 = xh + ((size_t)(b * XHW + yp0)) * XHW * CI;
  bf16* row1 = row0 + XHW * CI;

  __shared__ __align__(16) bf16 xls[2][128 * 64]; // 2 x 16 KB

  const bool z0 = (yp0 == 0);
  const bool z1 = (yp0 + 1 == XHW - 1);
  const float* xsrc = x + (((size_t)b * CI + lane) << 14) + px0;

  float v0[32], v1[32];
  if (!z0) {
    const float* s0 = xsrc + ((size_t)(yp0 - 1) << 7);
    #pragma unroll
    for (int j = 0; j < 8; ++j)
      *reinterpret_cast<f32x4*>(&v0[4 * j]) =
          *reinterpret_cast<const f32x4*>(s0 + 4 * j);
  }
  if (!z1) {
    const float* s1 = xsrc + ((size_t)yp0 << 7);
    #pragma unroll
    for (int j = 0; j < 8; ++j)
      *reinterpret_cast<f32x4*>(&v1[4 * j]) =
          *reinterpret_cast<const f32x4*>(s1 + 4 * j);
  }

  const int gq = lane >> 3;
  const int bo = (lane & 7) << 1;
  const bf16x8 zero8 = {};

  if (!z0) {
    #pragma unroll
    for (int p = 0; p < 32; ++p) {
      const int pxl = px0 + p;
      *reinterpret_cast<bf16*>(reinterpret_cast<char*>(xls[0]) + (pxl << 7) +
                               ((gq ^ (pxl & 7)) << 4) + bo) = (bf16)v0[p];
    }
  }
  __syncthreads();
  #pragma unroll
  for (int k = 0; k < 5; ++k) {
    const int it = k * 256 + tid;
    if (it >= XHW * 8) break;
    const int pxp = it >> 3, gr = it & 7;
    bf16x8 vv = zero8;
    if (!z0 && pxp >= 1 && pxp <= 128) {
      const int px = pxp - 1;
      vv = *reinterpret_cast<const bf16x8*>(
          reinterpret_cast<const char*>(xls[0]) + (px << 7) +
          ((gr ^ (px & 7)) << 4));
    }
    *reinterpret_cast<bf16x8*>(row0 + it * 8) = vv;
  }

  if (!z1) {
    #pragma unroll
    for (int p = 0; p < 32; ++p) {
      const int pxl = px0 + p;
      *reinterpret_cast<bf16*>(reinterpret_cast<char*>(xls[1]) + (pxl << 7) +
                               ((gq ^ (pxl & 7)) << 4) + bo) = (bf16)v1[p];
    }
  }
  __syncthreads();
  #pragma unroll
  for (int k = 0; k < 5; ++k) {
    const int it = k * 256 + tid;
    if (it >= XHW * 8) break;
    const int pxp = it >> 3, gr = it & 7;
    bf16x8 vv = zero8;
    if (!z1 && pxp >= 1 && pxp <= 128) {
      const int px = pxp - 1;
      vv = *reinterpret_cast<const bf16x8*>(
          reinterpret_cast<const char*>(xls[1]) + (px << 7) +
          ((gr ^ (px & 7)) << 4));
    }
    *reinterpret_cast<bf16x8*>(row1 + it * 8) = vv;
  }
}

// ---------------- conv v10 (implicit GEMM, bf16 MFMA, BARRIER-FREE) ----------------
// 1D grid 1024, XCD-swizzled. Block: 512 thr = 8 waves, 1 sample x 16x16
// px x all 64 co; wave wv owns output rows {2wv,2wv+1}. Each wave stages
// its own input rows y0+2wv-1..+2 (72 pl x 128B = 9216B private LDS) via
// exactly 9 global_load_lds; its own vmcnt(0) orders staging vs ds_read —
// NO __syncthreads. A-frags double-buffered in registers across taps.
__global__ __launch_bounds__(512, 4)
void conv_kernel(const bf16* __restrict__ xh, const bf16* __restrict__ wt2,
                 const float* __restrict__ bias, float* __restrict__ out) {
  __shared__ __align__(16) bf16 xt[8 * 4608]; // 73,728 B -> 2 blocks/CU

  const int id = (blockIdx.x & 7) * 128 + (blockIdx.x >> 3); // bijective
  const int b = id >> 6;
  const int x0 = (id & 7) * TS;
  const int y0 = ((id >> 3) & 7) * TS;

  const int tid = threadIdx.x;
  const int lane = tid & 63;
  const int wv = tid >> 6; // 0..7
  const int m = lane & 15;
  const int q = lane >> 4;

  const char* wbase = (const char*)wt2 + (size_t)b * 73728 + lane * 16;

  // ---- prefetch tap-0 A-fragments ----
  bf16x8 abuf[2][4][2];
  #pragma unroll
  for (int i = 0; i < 4; ++i)
    #pragma unroll
    for (int kh = 0; kh < 2; ++kh)
      abuf[0][i][kh] =
          *reinterpret_cast<const bf16x8*>(wbase + (i * 2 + kh) * 1024);

  // ---- per-wave private staging: rows y0+2wv .. y0+2wv+3 of xh (includes
  // the -1 halo via xh's border), 72 pl x 8 granules = 9 gll, no tail.
  // LDS slot (pl,gloc) <- xh granule gloc^(pl&7): read-side swizzle matches.
  {
    const char* xb = (const char*)xh +
                     (((size_t)(b * XHW + (y0 + 2 * wv))) * XHW + x0) * 128;
    char* ldsb = (char*)xt + wv * 9216;
    #pragma unroll
    for (int k = 0; k < 9; ++k) {
      const int e = k * 64 + lane;
      const int pl = e >> 3;
      const int gs = (e & 7) ^ (pl & 7);
      const int lr = (pl * 57) >> 10; // pl/18 (exact, pl<512)
      const int lx = pl - lr * 18;
      __builtin_amdgcn_global_load_lds(
          (gas_ptr)(xb + ((lr * XHW + lx) << 7) + (gs << 4)),
          (las_ptr)(ldsb + k * 1024), 16, 0, 0);
    }
  }

  f32x4 acc[4][2];
  #pragma unroll
  for (int i = 0; i < 4; ++i) {
    acc[i][0] = (f32x4){0.f, 0.f, 0.f, 0.f};
    acc[i][1] = (f32x4){0.f, 0.f, 0.f, 0.f};
  }

  // wait for OWN staging (and tap-0 A-frags) — per-wave, no barrier
  asm volatile("s_waitcnt vmcnt(0)" ::: "memory");
  __builtin_amdgcn_sched_barrier(0);

  const char* wxt = (const char*)xt + wv * 9216;

  #pragma unroll
  for (int tap = 0; tap < 9; ++tap) {
    const int cur = tap & 1, nxt = cur ^ 1; // compile-time after unroll
    if (tap < 8) { // prefetch next tap's A-frags; overlaps this tap's MFMAs
      const char* wt_n = wbase + (tap + 1) * 8192;
      #pragma unroll
      for (int i = 0; i < 4; ++i)
        #pragma unroll
        for (int kh = 0; kh < 2; ++kh)
          abuf[nxt][i][kh] =
              *reinterpret_cast<const bf16x8*>(wt_n + (i * 2 + kh) * 1024);
    }
    const int dy = (tap * 11) >> 5; // tap/3
    const int dx = tap - dy * 3;
    const int plb = dy * 18 + dx + m; // local pl = (dy+j)*18 + dx + m
    __builtin_amdgcn_s_setprio(1);
    #pragma unroll
    for (int kh = 0; kh < 2; ++kh) {
      const int qk = q + kh * 4;
      #pragma unroll
      for (int j = 0; j < 2; ++j) {
        const int pl = plb + j * 18;
        const bf16x8 bv = *reinterpret_cast<const bf16x8*>(
            wxt + (pl << 7) + ((qk ^ (pl & 7)) << 4));
        #pragma unroll
        for (int i = 0; i < 4; ++i)
          acc[i][j] = __builtin_amdgcn_mfma_f32_16x16x32_bf16(
              abuf[cur][i][kh], bv, acc[i][j], 0, 0, 0);
      }
    }
    __builtin_amdgcn_s_setprio(0);
  }

  // epilogue: D col = m (px), row = q*4+r (co in group); co = i*16 + q*4 + r
  const float* bp = bias + b * CO;
  float* ob =
      out + ((size_t)(b * CO) << 14) + (size_t)((y0 + 2 * wv) * WW + x0 + m);
  #pragma unroll
  for (int i = 0; i < 4; ++i)
    #pragma unroll
    for (int j = 0; j < 2; ++j)
      #pragma unroll
      for (int r = 0; r < 4; ++r) {
        const int co = i * 16 + q * 4 + r;
        float v = acc[i][j][r] + bp[co];
        ob[((size_t)co << 14) + j * WW] = fmaxf(v, 0.f);
      }
}

// ---------------- fallback conv (v4, reads raw x; ws too small) ----------------
__global__ __launch_bounds__(512, 4)
void conv_fb(const float* __restrict__ x, const bf16* __restrict__ wt2,
             const float* __restrict__ bias, float* __restrict__ out) {
  __shared__ __align__(16) bf16 xt[NPL * 64];

  const int id = (blockIdx.x & 7) * 128 + (blockIdx.x >> 3);
  const int b = id >> 6;
  const int x0 = (id & 7) * TS;
  const int y0 = ((id >> 3) & 7) * TS;

  const int tid = threadIdx.x;
  const int lane = tid & 63;
  const int wv = tid >> 6;
  const int m = lane & 15;
  const int q = lane >> 4;

  const char* wbase = (const char*)wt2 + (size_t)b * 73728 + lane * 16;

  bf16x8 abuf[2][4][2];
  #pragma unroll
  for (int i = 0; i < 4; ++i)
    #pragma unroll
    for (int kh = 0; kh < 2; ++kh)
      abuf[0][i][kh] =
          *reinterpret_cast<const bf16x8*>(wbase + (i * 2 + kh) * 1024);

  const float* xb = x + ((size_t)b << 20);
  for (int t = 0; t < 6; ++t) {
    const int it = min(tid + t * 512, NPL * 8 - 1);
    const int cig = ((it >> 2) * 810) >> 16;
    const int pl = it - cig * 324;
    const int py = (pl * 57) >> 10;
    const int px = pl - py * 18;
    int gy = y0 + py - 1, gx = x0 + px - 1;
    const bool inb = ((unsigned)gy < (unsigned)HH) & ((unsigned)gx < (unsigned)WW);
    gy = min(max(gy, 0), HH - 1);
    gx = min(max(gx, 0), WW - 1);
    const float* src = xb + ((size_t)cig << 17) + (gy << 7) + gx;
    bf16x8 v8;
    #pragma unroll
    for (int j = 0; j < 8; ++j)
      v8[j] = inb ? (bf16)src[(size_t)j << 14] : (bf16)0.f;
    if (!(t == 5 && tid >= NPL * 8 - 5 * 512))
      *reinterpret_cast<bf16x8*>(reinterpret_cast<char*>(xt) + (pl << 7) +
                                 ((cig ^ (pl & 7)) << 4)) = v8;
  }

  f32x4 acc[4][2];
  #pragma unroll
  for (int i = 0; i < 4; ++i) {
    acc[i][0] = (f32x4){0.f, 0.f, 0.f, 0.f};
    acc[i][1] = (f32x4){0.f, 0.f, 0.f, 0.f};
  }
  const int ty0 = wv * 2;
  __syncthreads();

  #pragma unroll
  for (int tap = 0; tap < 9; ++tap) {
    const int cur = tap & 1, nxt = cur ^ 1;
    if (tap < 8) {
      const char* wt_n = wbase + (tap + 1) * 8192;
      #pragma unroll
      for (int i = 0; i < 4; ++i)
        #pragma unroll
        for (int kh = 0; kh < 2; ++kh)
          abuf[nxt][i][kh] =
              *reinterpret_cast<const bf16x8*>(wt_n + (i * 2 + kh) * 1024);
    }
    const int dy = (tap * 11) >> 5;
    const int dx = tap - dy * 3;
    const int plb = (ty0 + dy) * 18 + dx + m;
    __builtin_amdgcn_s_setprio(1);
    #pragma unroll
    for (int kh = 0; kh < 2; ++kh) {
      const int qk = q + kh * 4;
      #pragma unroll
      for (int j = 0; j < 2; ++j) {
        const int pl = plb + j * 18;
        const bf16x8 bv = *reinterpret_cast<const bf16x8*>(
            reinterpret_cast<const char*>(xt) + (pl << 7) +
            ((qk ^ (pl & 7)) << 4));
        #pragma unroll
        for (int i = 0; i < 4; ++i)
          acc[i][j] = __builtin_amdgcn_mfma_f32_16x16x32_bf16(
              abuf[cur][i][kh], bv, acc[i][j], 0, 0, 0);
      }
    }
    __builtin_amdgcn_s_setprio(0);
  }

  const float* bp = bias + b * CO;
  float* ob = out + ((size_t)(b * CO) << 14) + (size_t)((y0 + ty0) * WW + x0 + m);
  #pragma unroll
  for (int i = 0; i < 4; ++i)
    #pragma unroll
    for (int j = 0; j < 2; ++j)
      #pragma unroll
      for (int r = 0; r < 4; ++r) {
        const int co = i * 16 + q * 4 + r;
        float v = acc[i][j][r] + bp[co];
        ob[((size_t)co << 14) + j * WW] = fmaxf(v, 0.f);
      }
}

extern "C" void kernel_launch(void* const* d_in, const int* in_sizes, int n_in,
                              void* d_out, int out_size, void* d_ws,
                              size_t ws_size, hipStream_t stream) {
  const float* x = (const float*)d_in[0];
  const float* z = (const float*)d_in[1];
  const float* W0 = (const float*)d_in[2];
  const float* b0 = (const float*)d_in[3];
  const float* W1 = (const float*)d_in[4];
  const float* b1 = (const float*)d_in[5];
  const float* W2 = (const float*)d_in[6];
  const float* b2 = (const float*)d_in[7];
  float* out = (float*)d_out;

  bf16* wt2 = (bf16*)d_ws;
  float* biases = (float*)((char*)d_ws + WT2_BYTES);
  bf16* xh = (bf16*)((char*)d_ws + WT2_BYTES + BIAS_BYTES);

  if (ws_size >= WS_NEED) {
    hipLaunchKernelGGL(prep_kernel, dim3(145 + NB * 65), dim3(256), 0, stream,
                       x, z, W0, b0, W1, b1, W2, b2, wt2, biases, xh);
    hipLaunchKernelGGL(conv_kernel, dim3(1024), dim3(512), 0, stream, xh, wt2,
                       biases, out);
  } else { // workspace too small: v4 path
    hipLaunchKernelGGL(prep_kernel, dim3(145), dim3(256), 0, stream, x, z, W0,
                       b0, W1, b1, W2, b2, wt2, biases, xh);
    hipLaunchKernelGGL(conv_fb, dim3(1024), dim3(512), 0, stream, x, wt2,
                       biases, out);
  }
}